// Round 4
// baseline (1263.147 us; speedup 1.0000x reference)
//
#include <hip/hip_runtime.h>

// MultilayeredNetwork: 8-step recurrent sparse net, CSR-per-call v2.
//   hist + scan -> row_ptr
//   pass A: bucket-scatter edges into per-128-row slabs (write-coalescing-friendly)
//   pass B: per-bucket LDS counting-scatter slab -> exact CSR order (L2-local)
//   per t: plane[t][n][b] = epilogue(sum_fx over row edges of val*state[col][b])
//          (16-lane group per row; 16-edge coalesced load + shfl broadcast; unrolled gathers)
//   final: transpose planes[t][n][b] -> out[b][n][t]
// Fixed-point int64 row accumulation (scale 2^44) => exact, order-independent,
// bitwise-deterministic across replays even though scatter orders vary.

#define N_NEURONS 100000
#define NNZ_CNT   3200000
#define N_SENSORY 5000
#define BATCH     16
#define T_LAYERS  8
#define THRESH    0.01f
#define STEEP     5.0f

#define NB (N_NEURONS * BATCH)
#define NT (N_NEURONS * T_LAYERS)
#define ST (N_SENSORY * T_LAYERS)

#define FXSCALE   17592186044416.0f        /* 2^44: exact fp32 scale (exp shift) */
#define FXINV     (1.0 / 17592186044416.0) /* double, exact */

#define CHUNK   1024
#define NCHUNK  ((N_NEURONS + CHUNK - 1) / CHUNK)     /* 98 */
#define BROWS   128                                    /* rows per bucket */
#define NBUCKET ((N_NEURONS + BROWS - 1) / BROWS)      /* 782 */

__device__ __forceinline__ float thresh_clamp_inp(float u) {
    u = (u >= THRESH) ? u : 0.0f;
    return fminf(u, 1.0f);
}
__device__ __forceinline__ float activate(float y) {
    y = (y >= THRESH) ? y : 0.0f;
    return tanhf(STEEP * y);
}

// ---------------- CSR build ----------------

// state0 (lives in planes[7] slot) + zero row counters.
__global__ void k_init(const float* __restrict__ inp, float* __restrict__ state0,
                       int* __restrict__ row_cnt) {
    int stride = gridDim.x * blockDim.x;
    for (int i = blockIdx.x * blockDim.x + threadIdx.x; i < NB; i += stride) {
        int n = i >> 4, b = i & 15;
        float v = 0.0f;
        if (n < N_SENSORY) v = thresh_clamp_inp(inp[b * ST + n * T_LAYERS + 0]);
        state0[i] = v;
        if (i < N_NEURONS) row_cnt[i] = 0;
    }
}

__global__ void k_hist(const int* __restrict__ rows, int* __restrict__ row_cnt) {
    int e = blockIdx.x * blockDim.x + threadIdx.x;
    if (e < NNZ_CNT) atomicAdd(&row_cnt[rows[e]], 1);
}

__global__ void k_scan_partial(const int* __restrict__ row_cnt, int* __restrict__ partial) {
    __shared__ int lds[256];
    int base = blockIdx.x * CHUNK + threadIdx.x * 4;
    int s = 0;
    #pragma unroll
    for (int k = 0; k < 4; ++k) {
        int idx = base + k;
        if (idx < N_NEURONS) s += row_cnt[idx];
    }
    lds[threadIdx.x] = s;
    __syncthreads();
    for (int off = 128; off > 0; off >>= 1) {
        if (threadIdx.x < off) lds[threadIdx.x] += lds[threadIdx.x + off];
        __syncthreads();
    }
    if (threadIdx.x == 0) partial[blockIdx.x] = lds[0];
}

__global__ void k_scan_offsets(int* __restrict__ partial, int* __restrict__ row_ptr) {
    __shared__ int lds[128];
    int v = (threadIdx.x < NCHUNK) ? partial[threadIdx.x] : 0;
    lds[threadIdx.x] = v;
    __syncthreads();
    for (int off = 1; off < 128; off <<= 1) {
        int add = (threadIdx.x >= off) ? lds[threadIdx.x - off] : 0;
        __syncthreads();
        lds[threadIdx.x] += add;
        __syncthreads();
    }
    if (threadIdx.x < NCHUNK) partial[threadIdx.x] = lds[threadIdx.x] - v;  // exclusive
    if (threadIdx.x == 0) row_ptr[N_NEURONS] = NNZ_CNT;
}

__global__ void k_scan_final(const int* __restrict__ row_cnt, const int* __restrict__ partial,
                             int* __restrict__ row_ptr) {
    __shared__ int lds[256];
    int base = blockIdx.x * CHUNK + threadIdx.x * 4;
    int c[4];
    int s = 0;
    #pragma unroll
    for (int k = 0; k < 4; ++k) {
        int idx = base + k;
        c[k] = (idx < N_NEURONS) ? row_cnt[idx] : 0;
        s += c[k];
    }
    lds[threadIdx.x] = s;
    __syncthreads();
    for (int off = 1; off < 256; off <<= 1) {
        int add = (threadIdx.x >= off) ? lds[threadIdx.x - off] : 0;
        __syncthreads();
        lds[threadIdx.x] += add;
        __syncthreads();
    }
    int pre = partial[blockIdx.x] + (lds[threadIdx.x] - s);  // exclusive prefix of elem 0
    #pragma unroll
    for (int k = 0; k < 4; ++k) {
        int idx = base + k;
        if (idx < N_NEURONS) {
            row_ptr[idx] = pre;
            pre += c[k];
        }
    }
}

// bucket cursors = row_ptr at bucket boundaries
__global__ void k_bcur(const int* __restrict__ row_ptr, int* __restrict__ bcur) {
    int k = blockIdx.x * blockDim.x + threadIdx.x;
    if (k < NBUCKET) bcur[k] = row_ptr[k * BROWS];
}

// pass A: scatter edge -> its bucket slab (unordered within slab).
// lo word packs (col << 7) | (row & 127); hi word = val bits.
__global__ void k_passA(const float* __restrict__ vals, const int* __restrict__ rows,
                        const int* __restrict__ cols, int* bcur,
                        int2* __restrict__ packed_tmp) {
    int e = blockIdx.x * blockDim.x + threadIdx.x;
    if (e < NNZ_CNT) {
        int r = rows[e];
        int k = r >> 7;
        int pos = atomicAdd(&bcur[k], 1);
        packed_tmp[pos] = make_int2((cols[e] << 7) | (r & (BROWS - 1)),
                                    __float_as_int(vals[e]));
    }
}

// pass B: per-bucket counting-scatter slab -> final CSR positions (L2-local 32KB slab).
__global__ void __launch_bounds__(256) k_passB(const int* __restrict__ row_ptr,
                                               const int2* __restrict__ packed_tmp,
                                               int2* __restrict__ packed) {
    __shared__ int cur[BROWS];
    int r0   = blockIdx.x * BROWS;
    int rend = min(r0 + BROWS, N_NEURONS);
    int nr   = rend - r0;
    if (threadIdx.x < nr) cur[threadIdx.x] = row_ptr[r0 + threadIdx.x];
    __syncthreads();
    int P0 = row_ptr[r0];
    int P1 = row_ptr[rend];
    for (int i = P0 + threadIdx.x; i < P1; i += blockDim.x) {
        int2 pe = packed_tmp[i];
        int rl = pe.x & (BROWS - 1);
        int dest = atomicAdd(&cur[rl], 1);
        packed[dest] = make_int2(pe.x >> 7, pe.y);
    }
}

// ---------------- fused per-layer SpMM + activation ----------------
// 16 lanes per row (one per batch). 16 edges loaded coalesced (one per lane),
// broadcast via shfl; inner loop unrolled -> 16 independent state gathers in flight.
__global__ void __launch_bounds__(256) k_layer(const int* __restrict__ row_ptr,
                                               const int2* __restrict__ packed,
                                               const float* __restrict__ state_in,
                                               const float* __restrict__ inp,
                                               float* __restrict__ plane_out,
                                               int t) {
    int tid = blockIdx.x * blockDim.x + threadIdx.x;
    int r = tid >> 4, b = tid & 15;
    if (r >= N_NEURONS) return;
    int s = row_ptr[r], e = row_ptr[r + 1];
    long long acc = 0;
    for (int base = s; base < e; base += 16) {
        int idx = base + b;
        int2 pe = (idx < e) ? packed[idx] : make_int2(0, 0);   // val=0 pad: exact no-op
        #pragma unroll
        for (int j = 0; j < 16; ++j) {
            int   c = __shfl(pe.x, j, 16);
            float v = __int_as_float(__shfl(pe.y, j, 16));
            float xv = state_in[c * BATCH + b];                 // coalesced 64B line / group
            acc += (long long)llrintf(v * xv * FXSCALE);
        }
    }
    float y = (float)((double)acc * FXINV);
    float a = activate(y);
    if (t < T_LAYERS - 1) {
        if (r < N_SENSORY) a += thresh_clamp_inp(inp[b * ST + r * T_LAYERS + (t + 1)]);
        a = fminf(a, 1.0f);                                     // off-sensory no-op (|tanh|<1)
    }
    plane_out[r * BATCH + b] = a;
}

// ---------------- planes[t][n][b] -> out[b][n][t] ----------------
__global__ void k_out(const float* __restrict__ planes, float* __restrict__ out) {
    int i = blockIdx.x * blockDim.x + threadIdx.x;   // i = n*16 + b
    if (i >= NB) return;
    int n = i >> 4, b = i & 15;
    float4 o0, o1;
    o0.x = planes[0 * NB + i]; o0.y = planes[1 * NB + i];
    o0.z = planes[2 * NB + i]; o0.w = planes[3 * NB + i];
    o1.x = planes[4 * NB + i]; o1.y = planes[5 * NB + i];
    o1.z = planes[6 * NB + i]; o1.w = planes[7 * NB + i];
    float4* dst = (float4*)&out[b * NT + n * T_LAYERS];   // 32B-aligned
    dst[0] = o0; dst[1] = o1;
}

// ---------------- fallback (atomic path, needs only 19.2 MB ws) ----------------
__global__ void k2_init(const float* __restrict__ inp, float* __restrict__ state,
                        long long* __restrict__ acc) {
    int stride = gridDim.x * blockDim.x;
    for (int i = blockIdx.x * blockDim.x + threadIdx.x; i < NB; i += stride) {
        int n = i >> 4, b = i & 15;
        float v = 0.0f;
        if (n < N_SENSORY) v = thresh_clamp_inp(inp[b * ST + n * T_LAYERS + 0]);
        state[i] = v;
        acc[i]   = 0LL;
    }
}
__global__ void __launch_bounds__(256) k2_spmm(const float* __restrict__ vals,
                                               const int* __restrict__ rows,
                                               const int* __restrict__ cols,
                                               const float* __restrict__ state,
                                               long long* acc) {
    int tid = blockIdx.x * blockDim.x + threadIdx.x;
    int b = tid & 15;
    int e = tid >> 4;
    int estride = (gridDim.x * blockDim.x) >> 4;
    for (; e < NNZ_CNT; e += estride) {
        int   c  = cols[e];
        float xv = state[c * BATCH + b];
        float v  = vals[e];
        long long fx = llrintf(v * xv * FXSCALE);
        if (fx != 0LL) {
            int r = rows[e];
            atomicAdd((unsigned long long*)&acc[r * BATCH + b], (unsigned long long)fx);
        }
    }
}
__global__ void k2_act_inject(long long* acc, const float* __restrict__ inp,
                              float* __restrict__ state, float* __restrict__ out, int t) {
    int stride = gridDim.x * blockDim.x;
    for (int i = blockIdx.x * blockDim.x + threadIdx.x; i < NB; i += stride) {
        int n = i >> 4, b = i & 15;
        float y = (float)((double)acc[i] * FXINV);
        acc[i] = 0LL;
        float v = activate(y);
        if (n < N_SENSORY) v += thresh_clamp_inp(inp[b * ST + n * T_LAYERS + (t + 1)]);
        v = fminf(v, 1.0f);
        state[i] = v;
        out[b * NT + n * T_LAYERS + t] = v;
    }
}
__global__ void k2_act_final(const long long* __restrict__ acc, float* __restrict__ out) {
    int stride = gridDim.x * blockDim.x;
    for (int i = blockIdx.x * blockDim.x + threadIdx.x; i < NB; i += stride) {
        int n = i >> 4, b = i & 15;
        float y = (float)((double)acc[i] * FXINV);
        out[b * NT + n * T_LAYERS + (T_LAYERS - 1)] = activate(y);
    }
}

extern "C" void kernel_launch(void* const* d_in, const int* in_sizes, int n_in,
                              void* d_out, int out_size, void* d_ws, size_t ws_size,
                              hipStream_t stream) {
    const float* inputs = (const float*)d_in[0];   // (16, 5000, 8) f32
    const float* vals   = (const float*)d_in[1];   // (3.2M,) f32
    const int*   rows   = (const int*)  d_in[2];   // (3.2M,) i32
    const int*   cols   = (const int*)  d_in[3];   // (3.2M,) i32
    float* out = (float*)d_out;

    // ws layout (CSR path)
    const size_t sz_planes = (size_t)T_LAYERS * NB * 4;   // 51.2 MB
    const size_t sz_packed = (size_t)NNZ_CNT * 8;         // 25.6 MB
    const size_t sz_rowptr = ((size_t)N_NEURONS + 2) * 4;
    const size_t sz_rowcnt = (size_t)N_NEURONS * 4;
    const size_t sz_bcur   = (size_t)((NBUCKET + 128) * 4);
    const size_t sz_part   = 512;
    const size_t REQ = sz_planes + sz_packed + sz_rowptr + sz_rowcnt + sz_bcur + sz_part;

    const int block = 256;

    if (ws_size >= REQ) {
        char* ws = (char*)d_ws;
        float* planes  = (float*)ws;
        int2*  packed  = (int2*)(ws + sz_planes);
        int*   row_ptr = (int*)(ws + sz_planes + sz_packed);
        int*   row_cnt = (int*)(ws + sz_planes + sz_packed + sz_rowptr);
        int*   bcur    = (int*)(ws + sz_planes + sz_packed + sz_rowptr + sz_rowcnt);
        int*   partial = (int*)(ws + sz_planes + sz_packed + sz_rowptr + sz_rowcnt + sz_bcur);
        float* state0  = planes + (size_t)(T_LAYERS - 1) * NB;  // planes[7] slot
        int2*  packed_tmp = (int2*)planes;  // aliases planes[0..3]; dead before layer 0 runs

        const int grid_nb  = (NB + block - 1) / block;           // 6250
        const int grid_nnz = (NNZ_CNT + block - 1) / block;      // 12500

        k_init<<<grid_nb, block, 0, stream>>>(inputs, state0, row_cnt);
        k_hist<<<grid_nnz, block, 0, stream>>>(rows, row_cnt);
        k_scan_partial<<<NCHUNK, 256, 0, stream>>>(row_cnt, partial);
        k_scan_offsets<<<1, 128, 0, stream>>>(partial, row_ptr);
        k_scan_final<<<NCHUNK, 256, 0, stream>>>(row_cnt, partial, row_ptr);
        k_bcur<<<(NBUCKET + block - 1) / block, block, 0, stream>>>(row_ptr, bcur);
        k_passA<<<grid_nnz, block, 0, stream>>>(vals, rows, cols, bcur, packed_tmp);
        k_passB<<<NBUCKET, 256, 0, stream>>>(row_ptr, packed_tmp, packed);

        for (int t = 0; t < T_LAYERS; ++t) {
            const float* sin_ = (t == 0) ? state0 : planes + (size_t)(t - 1) * NB;
            k_layer<<<grid_nb, block, 0, stream>>>(row_ptr, packed, sin_, inputs,
                                                   planes + (size_t)t * NB, t);
        }
        k_out<<<grid_nb, block, 0, stream>>>(planes, out);
    } else {
        // fallback: atomic path (19.2 MB ws)
        long long* acc   = (long long*)d_ws;
        float*     state = (float*)(acc + NB);
        const int grid_ew = 2048, grid_sp = 2048;
        k2_init<<<grid_ew, block, 0, stream>>>(inputs, state, acc);
        for (int t = 0; t < T_LAYERS; ++t) {
            k2_spmm<<<grid_sp, block, 0, stream>>>(vals, rows, cols, state, acc);
            if (t < T_LAYERS - 1)
                k2_act_inject<<<grid_ew, block, 0, stream>>>(acc, inputs, state, out, t);
            else
                k2_act_final<<<grid_ew, block, 0, stream>>>(acc, out);
        }
    }
}

// Round 5
// 547.781 us; speedup vs baseline: 2.3059x; 2.3059x over previous
//
#include <hip/hip_runtime.h>

// MultilayeredNetwork: 8-step recurrent sparse net, CSR-per-call v3.
//   hist + scan -> row_ptr
//   pass A: LDS-binned bucket scatter (block-local count -> bulk cursor reserve -> place)
//   pass B: per-bucket LDS counting-scatter slab -> exact CSR grouping (L2-local)
//   per t: plane[t][n][b] = epilogue(sum_fx over row edges of val*state[col][b])
//          (16-lane group per row; 16-edge coalesced load + shfl broadcast)
//   final: transpose planes[t][n][b] -> out[b][n][t]
// Fixed-point int64 row accumulation (scale 2^44) => exact, order-independent,
// bitwise-deterministic across replays even though scatter orders vary.

#define N_NEURONS 100000
#define NNZ_CNT   3200000
#define N_SENSORY 5000
#define BATCH     16
#define T_LAYERS  8
#define THRESH    0.01f
#define STEEP     5.0f

#define NB (N_NEURONS * BATCH)
#define NT (N_NEURONS * T_LAYERS)
#define ST (N_SENSORY * T_LAYERS)

#define FXSCALE   17592186044416.0f        /* 2^44: exact fp32 scale (exp shift) */
#define FXINV     (1.0 / 17592186044416.0) /* double, exact */

#define CHUNK   1024
#define NCHUNK  ((N_NEURONS + CHUNK - 1) / CHUNK)     /* 98 */

#define LBITS   9
#define BROWS   (1 << LBITS)                           /* 512 rows per bucket */
#define NBUCKET ((N_NEURONS + BROWS - 1) / BROWS)      /* 196 */
#define EPB     16384                                  /* edges per passA block */
#define NBLK_A  ((NNZ_CNT + EPB - 1) / EPB)            /* 196 */

__device__ __forceinline__ float thresh_clamp_inp(float u) {
    u = (u >= THRESH) ? u : 0.0f;
    return fminf(u, 1.0f);
}
__device__ __forceinline__ float activate(float y) {
    y = (y >= THRESH) ? y : 0.0f;
    return tanhf(STEEP * y);
}

// ---------------- CSR build ----------------

// state0 (lives in planes[7] slot) + zero row counters.
__global__ void k_init(const float* __restrict__ inp, float* __restrict__ state0,
                       int* __restrict__ row_cnt) {
    int stride = gridDim.x * blockDim.x;
    for (int i = blockIdx.x * blockDim.x + threadIdx.x; i < NB; i += stride) {
        int n = i >> 4, b = i & 15;
        float v = 0.0f;
        if (n < N_SENSORY) v = thresh_clamp_inp(inp[b * ST + n * T_LAYERS + 0]);
        state0[i] = v;
        if (i < N_NEURONS) row_cnt[i] = 0;
    }
}

__global__ void k_hist(const int* __restrict__ rows, int* __restrict__ row_cnt) {
    int e = blockIdx.x * blockDim.x + threadIdx.x;
    if (e < NNZ_CNT) atomicAdd(&row_cnt[rows[e]], 1);
}

__global__ void k_scan_partial(const int* __restrict__ row_cnt, int* __restrict__ partial) {
    __shared__ int lds[256];
    int base = blockIdx.x * CHUNK + threadIdx.x * 4;
    int s = 0;
    #pragma unroll
    for (int k = 0; k < 4; ++k) {
        int idx = base + k;
        if (idx < N_NEURONS) s += row_cnt[idx];
    }
    lds[threadIdx.x] = s;
    __syncthreads();
    for (int off = 128; off > 0; off >>= 1) {
        if (threadIdx.x < off) lds[threadIdx.x] += lds[threadIdx.x + off];
        __syncthreads();
    }
    if (threadIdx.x == 0) partial[blockIdx.x] = lds[0];
}

__global__ void k_scan_offsets(int* __restrict__ partial, int* __restrict__ row_ptr) {
    __shared__ int lds[128];
    int v = (threadIdx.x < NCHUNK) ? partial[threadIdx.x] : 0;
    lds[threadIdx.x] = v;
    __syncthreads();
    for (int off = 1; off < 128; off <<= 1) {
        int add = (threadIdx.x >= off) ? lds[threadIdx.x - off] : 0;
        __syncthreads();
        lds[threadIdx.x] += add;
        __syncthreads();
    }
    if (threadIdx.x < NCHUNK) partial[threadIdx.x] = lds[threadIdx.x] - v;  // exclusive
    if (threadIdx.x == 0) row_ptr[N_NEURONS] = NNZ_CNT;
}

__global__ void k_scan_final(const int* __restrict__ row_cnt, const int* __restrict__ partial,
                             int* __restrict__ row_ptr) {
    __shared__ int lds[256];
    int base = blockIdx.x * CHUNK + threadIdx.x * 4;
    int c[4];
    int s = 0;
    #pragma unroll
    for (int k = 0; k < 4; ++k) {
        int idx = base + k;
        c[k] = (idx < N_NEURONS) ? row_cnt[idx] : 0;
        s += c[k];
    }
    lds[threadIdx.x] = s;
    __syncthreads();
    for (int off = 1; off < 256; off <<= 1) {
        int add = (threadIdx.x >= off) ? lds[threadIdx.x - off] : 0;
        __syncthreads();
        lds[threadIdx.x] += add;
        __syncthreads();
    }
    int pre = partial[blockIdx.x] + (lds[threadIdx.x] - s);  // exclusive prefix of elem 0
    #pragma unroll
    for (int k = 0; k < 4; ++k) {
        int idx = base + k;
        if (idx < N_NEURONS) {
            row_ptr[idx] = pre;
            pre += c[k];
        }
    }
}

// bucket cursors = row_ptr at bucket boundaries
__global__ void k_bcur(const int* __restrict__ row_ptr, int* __restrict__ bcur) {
    int k = blockIdx.x * blockDim.x + threadIdx.x;
    if (k < NBUCKET) bcur[k] = row_ptr[k * BROWS];
}

// pass A: two-level scatter. Block bins EPB edges in LDS, bulk-reserves slab
// space with ONE global atomic per (bucket, block), then places edges.
// lo word packs (col << LBITS) | (row & (BROWS-1)); hi word = val bits.
__global__ void __launch_bounds__(1024) k_passA(const float* __restrict__ vals,
                                                const int* __restrict__ rows,
                                                const int* __restrict__ cols,
                                                int* bcur,
                                                int2* __restrict__ packed_tmp) {
    __shared__ int cnt[NBUCKET];
    __shared__ int base[NBUCKET];
    const int e0 = blockIdx.x * EPB;
    for (int i = threadIdx.x; i < NBUCKET; i += 1024) cnt[i] = 0;
    __syncthreads();
    // phase 1: count
    #pragma unroll
    for (int i = 0; i < EPB / 1024; ++i) {
        int e = e0 + i * 1024 + threadIdx.x;
        if (e < NNZ_CNT) atomicAdd(&cnt[rows[e] >> LBITS], 1);
    }
    __syncthreads();
    // phase 2: bulk reserve; reuse cnt as local cursor
    for (int i = threadIdx.x; i < NBUCKET; i += 1024) {
        int c = cnt[i];
        base[i] = (c > 0) ? atomicAdd(&bcur[i], c) : 0;
        cnt[i] = 0;
    }
    __syncthreads();
    // phase 3: place (edges re-read; L2-hot)
    #pragma unroll
    for (int i = 0; i < EPB / 1024; ++i) {
        int e = e0 + i * 1024 + threadIdx.x;
        if (e < NNZ_CNT) {
            int r = rows[e];
            int k = r >> LBITS;
            int pos = base[k] + atomicAdd(&cnt[k], 1);
            packed_tmp[pos] = make_int2((cols[e] << LBITS) | (r & (BROWS - 1)),
                                        __float_as_int(vals[e]));
        }
    }
}

// pass B: per-bucket counting-scatter slab -> final CSR positions (L2-local ~131KB slab).
__global__ void __launch_bounds__(1024) k_passB(const int* __restrict__ row_ptr,
                                                const int2* __restrict__ packed_tmp,
                                                int2* __restrict__ packed) {
    __shared__ int cur[BROWS];
    int r0   = blockIdx.x * BROWS;
    int rend = min(r0 + BROWS, N_NEURONS);
    int nr   = rend - r0;
    for (int i = threadIdx.x; i < nr; i += 1024) cur[i] = row_ptr[r0 + i];
    __syncthreads();
    int P0 = row_ptr[r0];
    int P1 = row_ptr[rend];
    for (int i = P0 + threadIdx.x; i < P1; i += 1024) {
        int2 pe = packed_tmp[i];
        int rl = pe.x & (BROWS - 1);
        int dest = atomicAdd(&cur[rl], 1);
        packed[dest] = make_int2(pe.x >> LBITS, pe.y);
    }
}

// ---------------- fused per-layer SpMM + activation ----------------
// 16 lanes per row (one per batch). 16 edges loaded coalesced (one per lane),
// broadcast via shfl; inner loop unrolled -> 16 independent state gathers in flight.
__global__ void __launch_bounds__(256) k_layer(const int* __restrict__ row_ptr,
                                               const int2* __restrict__ packed,
                                               const float* __restrict__ state_in,
                                               const float* __restrict__ inp,
                                               float* __restrict__ plane_out,
                                               int t) {
    int tid = blockIdx.x * blockDim.x + threadIdx.x;
    int r = tid >> 4, b = tid & 15;
    if (r >= N_NEURONS) return;
    int s = row_ptr[r], e = row_ptr[r + 1];
    long long acc = 0;
    for (int base = s; base < e; base += 16) {
        int idx = base + b;
        int2 pe = (idx < e) ? packed[idx] : make_int2(0, 0);   // val=0 pad: exact no-op
        #pragma unroll
        for (int j = 0; j < 16; ++j) {
            int   c = __shfl(pe.x, j, 16);
            float v = __int_as_float(__shfl(pe.y, j, 16));
            float xv = state_in[c * BATCH + b];                 // coalesced 64B line / group
            acc += (long long)llrintf(v * xv * FXSCALE);
        }
    }
    float y = (float)((double)acc * FXINV);
    float a = activate(y);
    if (t < T_LAYERS - 1) {
        if (r < N_SENSORY) a += thresh_clamp_inp(inp[b * ST + r * T_LAYERS + (t + 1)]);
        a = fminf(a, 1.0f);                                     // off-sensory no-op (|tanh|<1)
    }
    plane_out[r * BATCH + b] = a;
}

// ---------------- planes[t][n][b] -> out[b][n][t] ----------------
__global__ void k_out(const float* __restrict__ planes, float* __restrict__ out) {
    int i = blockIdx.x * blockDim.x + threadIdx.x;   // i = n*16 + b
    if (i >= NB) return;
    int n = i >> 4, b = i & 15;
    float4 o0, o1;
    o0.x = planes[0 * NB + i]; o0.y = planes[1 * NB + i];
    o0.z = planes[2 * NB + i]; o0.w = planes[3 * NB + i];
    o1.x = planes[4 * NB + i]; o1.y = planes[5 * NB + i];
    o1.z = planes[6 * NB + i]; o1.w = planes[7 * NB + i];
    float4* dst = (float4*)&out[b * NT + n * T_LAYERS];   // 32B-aligned
    dst[0] = o0; dst[1] = o1;
}

// ---------------- fallback (atomic path, needs only 19.2 MB ws) ----------------
__global__ void k2_init(const float* __restrict__ inp, float* __restrict__ state,
                        long long* __restrict__ acc) {
    int stride = gridDim.x * blockDim.x;
    for (int i = blockIdx.x * blockDim.x + threadIdx.x; i < NB; i += stride) {
        int n = i >> 4, b = i & 15;
        float v = 0.0f;
        if (n < N_SENSORY) v = thresh_clamp_inp(inp[b * ST + n * T_LAYERS + 0]);
        state[i] = v;
        acc[i]   = 0LL;
    }
}
__global__ void __launch_bounds__(256) k2_spmm(const float* __restrict__ vals,
                                               const int* __restrict__ rows,
                                               const int* __restrict__ cols,
                                               const float* __restrict__ state,
                                               long long* acc) {
    int tid = blockIdx.x * blockDim.x + threadIdx.x;
    int b = tid & 15;
    int e = tid >> 4;
    int estride = (gridDim.x * blockDim.x) >> 4;
    for (; e < NNZ_CNT; e += estride) {
        int   c  = cols[e];
        float xv = state[c * BATCH + b];
        float v  = vals[e];
        long long fx = llrintf(v * xv * FXSCALE);
        if (fx != 0LL) {
            int r = rows[e];
            atomicAdd((unsigned long long*)&acc[r * BATCH + b], (unsigned long long)fx);
        }
    }
}
__global__ void k2_act_inject(long long* acc, const float* __restrict__ inp,
                              float* __restrict__ state, float* __restrict__ out, int t) {
    int stride = gridDim.x * blockDim.x;
    for (int i = blockIdx.x * blockDim.x + threadIdx.x; i < NB; i += stride) {
        int n = i >> 4, b = i & 15;
        float y = (float)((double)acc[i] * FXINV);
        acc[i] = 0LL;
        float v = activate(y);
        if (n < N_SENSORY) v += thresh_clamp_inp(inp[b * ST + n * T_LAYERS + (t + 1)]);
        v = fminf(v, 1.0f);
        state[i] = v;
        out[b * NT + n * T_LAYERS + t] = v;
    }
}
__global__ void k2_act_final(const long long* __restrict__ acc, float* __restrict__ out) {
    int stride = gridDim.x * blockDim.x;
    for (int i = blockIdx.x * blockDim.x + threadIdx.x; i < NB; i += stride) {
        int n = i >> 4, b = i & 15;
        float y = (float)((double)acc[i] * FXINV);
        out[b * NT + n * T_LAYERS + (T_LAYERS - 1)] = activate(y);
    }
}

extern "C" void kernel_launch(void* const* d_in, const int* in_sizes, int n_in,
                              void* d_out, int out_size, void* d_ws, size_t ws_size,
                              hipStream_t stream) {
    const float* inputs = (const float*)d_in[0];   // (16, 5000, 8) f32
    const float* vals   = (const float*)d_in[1];   // (3.2M,) f32
    const int*   rows   = (const int*)  d_in[2];   // (3.2M,) i32
    const int*   cols   = (const int*)  d_in[3];   // (3.2M,) i32
    float* out = (float*)d_out;

    // ws layout (CSR path)
    const size_t sz_planes = (size_t)T_LAYERS * NB * 4;   // 51.2 MB
    const size_t sz_packed = (size_t)NNZ_CNT * 8;         // 25.6 MB
    const size_t sz_rowptr = ((size_t)N_NEURONS + 2) * 4;
    const size_t sz_rowcnt = (size_t)N_NEURONS * 4;
    const size_t sz_bcur   = (size_t)((NBUCKET + 128) * 4);
    const size_t sz_part   = 512;
    const size_t REQ = sz_planes + sz_packed + sz_rowptr + sz_rowcnt + sz_bcur + sz_part;

    const int block = 256;

    if (ws_size >= REQ) {
        char* ws = (char*)d_ws;
        float* planes  = (float*)ws;
        int2*  packed  = (int2*)(ws + sz_planes);
        int*   row_ptr = (int*)(ws + sz_planes + sz_packed);
        int*   row_cnt = (int*)(ws + sz_planes + sz_packed + sz_rowptr);
        int*   bcur    = (int*)(ws + sz_planes + sz_packed + sz_rowptr + sz_rowcnt);
        int*   partial = (int*)(ws + sz_planes + sz_packed + sz_rowptr + sz_rowcnt + sz_bcur);
        float* state0  = planes + (size_t)(T_LAYERS - 1) * NB;  // planes[7] slot
        int2*  packed_tmp = (int2*)planes;  // aliases planes[0..3]; dead before layer 0 runs

        const int grid_nb  = (NB + block - 1) / block;           // 6250
        const int grid_nnz = (NNZ_CNT + block - 1) / block;      // 12500

        k_init<<<grid_nb, block, 0, stream>>>(inputs, state0, row_cnt);
        k_hist<<<grid_nnz, block, 0, stream>>>(rows, row_cnt);
        k_scan_partial<<<NCHUNK, 256, 0, stream>>>(row_cnt, partial);
        k_scan_offsets<<<1, 128, 0, stream>>>(partial, row_ptr);
        k_scan_final<<<NCHUNK, 256, 0, stream>>>(row_cnt, partial, row_ptr);
        k_bcur<<<1, 256, 0, stream>>>(row_ptr, bcur);
        k_passA<<<NBLK_A, 1024, 0, stream>>>(vals, rows, cols, bcur, packed_tmp);
        k_passB<<<NBUCKET, 1024, 0, stream>>>(row_ptr, packed_tmp, packed);

        for (int t = 0; t < T_LAYERS; ++t) {
            const float* sin_ = (t == 0) ? state0 : planes + (size_t)(t - 1) * NB;
            k_layer<<<grid_nb, block, 0, stream>>>(row_ptr, packed, sin_, inputs,
                                                   planes + (size_t)t * NB, t);
        }
        k_out<<<grid_nb, block, 0, stream>>>(planes, out);
    } else {
        // fallback: atomic path (19.2 MB ws)
        long long* acc   = (long long*)d_ws;
        float*     state = (float*)(acc + NB);
        const int grid_ew = 2048, grid_sp = 2048;
        k2_init<<<grid_ew, block, 0, stream>>>(inputs, state, acc);
        for (int t = 0; t < T_LAYERS; ++t) {
            k2_spmm<<<grid_sp, block, 0, stream>>>(vals, rows, cols, state, acc);
            if (t < T_LAYERS - 1)
                k2_act_inject<<<grid_ew, block, 0, stream>>>(acc, inputs, state, out, t);
            else
                k2_act_final<<<grid_ew, block, 0, stream>>>(acc, out);
        }
    }
}

// Round 6
// 426.581 us; speedup vs baseline: 2.9611x; 1.2841x over previous
//
#include <hip/hip_runtime.h>

// MultilayeredNetwork: 8-step recurrent sparse net, CSR-per-call v4.
//   bucket-count (196 bins, LDS + bulk atomics) -> bucket scan -> row_ptr-free build:
//   pass A: LDS-binned bucket scatter (block count -> bulk cursor reserve -> place)
//   pass B: per-bucket LDS row-histogram + scan -> row_ptr AND exact CSR scatter (L2-local)
//   per t: plane[t][n][b] = epilogue(sum_fx over row edges of val*state[col][b])
//          (16-lane group per row; 16-edge coalesced load + shfl broadcast)
//   final: transpose planes[t][n][b] -> out[b][n][t]
// Fixed-point int64 row accumulation (scale 2^44) => exact, order-independent,
// bitwise-deterministic across replays even though scatter orders vary.
// NOTE (measured R5): device-scope atomics are memory-side (~32B each) -> the
// whole design minimizes global atomic COUNT, not just contention.

#define N_NEURONS 100000
#define NNZ_CNT   3200000
#define N_SENSORY 5000
#define BATCH     16
#define T_LAYERS  8
#define THRESH    0.01f
#define STEEP     5.0f

#define NB (N_NEURONS * BATCH)
#define NT (N_NEURONS * T_LAYERS)
#define ST (N_SENSORY * T_LAYERS)

#define FXSCALE   17592186044416.0f        /* 2^44: exact fp32 scale (exp shift) */
#define FXINV     (1.0 / 17592186044416.0) /* double, exact */

#define LBITS   9
#define BROWS   (1 << LBITS)                           /* 512 rows per bucket */
#define NBUCKET ((N_NEURONS + BROWS - 1) / BROWS)      /* 196 */
#define EPB     8192                                   /* edges per build block */
#define NBLK_A  ((NNZ_CNT + EPB - 1) / EPB)            /* 391 */

__device__ __forceinline__ float thresh_clamp_inp(float u) {
    u = (u >= THRESH) ? u : 0.0f;
    return fminf(u, 1.0f);
}
__device__ __forceinline__ float activate(float y) {
    y = (y >= THRESH) ? y : 0.0f;
    return tanhf(STEEP * y);
}

// ---------------- CSR build ----------------

// state0 (lives in planes[7] slot) + zero bucket totals.
__global__ void k_init(const float* __restrict__ inp, float* __restrict__ state0,
                       int* __restrict__ btotal) {
    int stride = gridDim.x * blockDim.x;
    for (int i = blockIdx.x * blockDim.x + threadIdx.x; i < NB; i += stride) {
        int n = i >> 4, b = i & 15;
        float v = 0.0f;
        if (n < N_SENSORY) v = thresh_clamp_inp(inp[b * ST + n * T_LAYERS + 0]);
        state0[i] = v;
        if (i < NBUCKET) btotal[i] = 0;
    }
}

// 196-bin bucket histogram: LDS count per block, one global atomic per (bucket, block).
__global__ void __launch_bounds__(1024) k_bcount(const int* __restrict__ rows,
                                                 int* __restrict__ btotal) {
    __shared__ int cnt[NBUCKET];
    const int e0 = blockIdx.x * EPB;
    for (int i = threadIdx.x; i < NBUCKET; i += 1024) cnt[i] = 0;
    __syncthreads();
    #pragma unroll
    for (int i = 0; i < EPB / 1024; ++i) {
        int e = e0 + i * 1024 + threadIdx.x;
        if (e < NNZ_CNT) atomicAdd(&cnt[rows[e] >> LBITS], 1);
    }
    __syncthreads();
    for (int i = threadIdx.x; i < NBUCKET; i += 1024)
        if (cnt[i]) atomicAdd(&btotal[i], cnt[i]);
}

// single-block exclusive scan of 196 bucket totals -> bbase, bcur.
__global__ void k_bscan(const int* __restrict__ btotal, int* __restrict__ bbase,
                        int* __restrict__ bcur, int* __restrict__ row_ptr) {
    __shared__ int lds[256];
    int tid = threadIdx.x;
    int v = (tid < NBUCKET) ? btotal[tid] : 0;
    lds[tid] = v;
    __syncthreads();
    for (int off = 1; off < 256; off <<= 1) {
        int add = (tid >= off) ? lds[tid - off] : 0;
        __syncthreads();
        lds[tid] += add;
        __syncthreads();
    }
    if (tid < NBUCKET) {
        bbase[tid] = lds[tid] - v;     // exclusive prefix
        bcur[tid]  = lds[tid] - v;
    }
    if (tid == 0) { bbase[NBUCKET] = NNZ_CNT; row_ptr[N_NEURONS] = NNZ_CNT; }
}

// pass A: two-level scatter. Block bins EPB edges in LDS, bulk-reserves slab
// space with ONE global atomic per (bucket, block), then places edges.
// lo word packs (col << LBITS) | (row & (BROWS-1)); hi word = val bits.
__global__ void __launch_bounds__(1024) k_passA(const float* __restrict__ vals,
                                                const int* __restrict__ rows,
                                                const int* __restrict__ cols,
                                                int* bcur,
                                                int2* __restrict__ packed_tmp) {
    __shared__ int cnt[NBUCKET];
    __shared__ int base[NBUCKET];
    const int e0 = blockIdx.x * EPB;
    for (int i = threadIdx.x; i < NBUCKET; i += 1024) cnt[i] = 0;
    __syncthreads();
    // phase 1: count
    #pragma unroll
    for (int i = 0; i < EPB / 1024; ++i) {
        int e = e0 + i * 1024 + threadIdx.x;
        if (e < NNZ_CNT) atomicAdd(&cnt[rows[e] >> LBITS], 1);
    }
    __syncthreads();
    // phase 2: bulk reserve; reuse cnt as local cursor
    for (int i = threadIdx.x; i < NBUCKET; i += 1024) {
        int c = cnt[i];
        base[i] = (c > 0) ? atomicAdd(&bcur[i], c) : 0;
        cnt[i] = 0;
    }
    __syncthreads();
    // phase 3: place (edges re-read; L2-hot)
    #pragma unroll
    for (int i = 0; i < EPB / 1024; ++i) {
        int e = e0 + i * 1024 + threadIdx.x;
        if (e < NNZ_CNT) {
            int r = rows[e];
            int k = r >> LBITS;
            int pos = base[k] + atomicAdd(&cnt[k], 1);
            packed_tmp[pos] = make_int2((cols[e] << LBITS) | (r & (BROWS - 1)),
                                        __float_as_int(vals[e]));
        }
    }
}

// pass B: per-bucket slab -> LDS row histogram + scan -> row_ptr AND final scatter.
__global__ void __launch_bounds__(1024) k_passB(const int* __restrict__ bbase,
                                                const int2* __restrict__ packed_tmp,
                                                int2* __restrict__ packed,
                                                int* __restrict__ row_ptr) {
    __shared__ int cnt[BROWS];
    __shared__ int scn[BROWS];
    const int tid = threadIdx.x;
    const int k  = blockIdx.x;
    const int r0 = k * BROWS;
    const int nr = min(BROWS, N_NEURONS - r0);
    const int P0 = bbase[k], P1 = bbase[k + 1];
    for (int i = tid; i < BROWS; i += 1024) cnt[i] = 0;
    __syncthreads();
    // row histogram of the slab
    for (int i = P0 + tid; i < P1; i += 1024)
        atomicAdd(&cnt[packed_tmp[i].x & (BROWS - 1)], 1);
    __syncthreads();
    // inclusive Hillis-Steele scan over 512 bins (threads 0..511)
    if (tid < BROWS) scn[tid] = cnt[tid];
    __syncthreads();
    for (int off = 1; off < BROWS; off <<= 1) {
        int add = (tid < BROWS && tid >= off) ? scn[tid - off] : 0;
        __syncthreads();
        if (tid < BROWS) scn[tid] += add;
        __syncthreads();
    }
    // exclusive base per row -> row_ptr + cursor
    if (tid < BROWS) {
        int ex = P0 + scn[tid] - cnt[tid];
        if (tid < nr) row_ptr[r0 + tid] = ex;
        scn[tid] = ex;                      // cursor (cnt left intact until here)
    }
    __syncthreads();
    // counting scatter to final CSR positions
    for (int i = P0 + tid; i < P1; i += 1024) {
        int2 pe = packed_tmp[i];
        int d = atomicAdd(&scn[pe.x & (BROWS - 1)], 1);
        packed[d] = make_int2(pe.x >> LBITS, pe.y);
    }
}

// ---------------- fused per-layer SpMM + activation ----------------
// 16 lanes per row (one per batch). 16 edges loaded coalesced (one per lane),
// broadcast via shfl; inner loop unrolled -> 16 independent state gathers in flight.
__global__ void __launch_bounds__(256) k_layer(const int* __restrict__ row_ptr,
                                               const int2* __restrict__ packed,
                                               const float* __restrict__ state_in,
                                               const float* __restrict__ inp,
                                               float* __restrict__ plane_out,
                                               int t) {
    int tid = blockIdx.x * blockDim.x + threadIdx.x;
    int r = tid >> 4, b = tid & 15;
    if (r >= N_NEURONS) return;
    int s = row_ptr[r], e = row_ptr[r + 1];
    long long acc = 0;
    for (int base = s; base < e; base += 16) {
        int idx = base + b;
        int2 pe = (idx < e) ? packed[idx] : make_int2(0, 0);   // val=0 pad: exact no-op
        #pragma unroll
        for (int j = 0; j < 16; ++j) {
            int   c = __shfl(pe.x, j, 16);
            float v = __int_as_float(__shfl(pe.y, j, 16));
            float xv = state_in[c * BATCH + b];                 // coalesced 64B line / group
            acc += (long long)llrintf(v * xv * FXSCALE);
        }
    }
    float y = (float)((double)acc * FXINV);
    float a = activate(y);
    if (t < T_LAYERS - 1) {
        if (r < N_SENSORY) a += thresh_clamp_inp(inp[b * ST + r * T_LAYERS + (t + 1)]);
        a = fminf(a, 1.0f);                                     // off-sensory no-op (|tanh|<1)
    }
    plane_out[r * BATCH + b] = a;
}

// ---------------- planes[t][n][b] -> out[b][n][t] ----------------
__global__ void k_out(const float* __restrict__ planes, float* __restrict__ out) {
    int i = blockIdx.x * blockDim.x + threadIdx.x;   // i = n*16 + b
    if (i >= NB) return;
    int n = i >> 4, b = i & 15;
    float4 o0, o1;
    o0.x = planes[0 * NB + i]; o0.y = planes[1 * NB + i];
    o0.z = planes[2 * NB + i]; o0.w = planes[3 * NB + i];
    o1.x = planes[4 * NB + i]; o1.y = planes[5 * NB + i];
    o1.z = planes[6 * NB + i]; o1.w = planes[7 * NB + i];
    float4* dst = (float4*)&out[b * NT + n * T_LAYERS];   // 32B-aligned
    dst[0] = o0; dst[1] = o1;
}

// ---------------- fallback (atomic path, needs only 19.2 MB ws) ----------------
__global__ void k2_init(const float* __restrict__ inp, float* __restrict__ state,
                        long long* __restrict__ acc) {
    int stride = gridDim.x * blockDim.x;
    for (int i = blockIdx.x * blockDim.x + threadIdx.x; i < NB; i += stride) {
        int n = i >> 4, b = i & 15;
        float v = 0.0f;
        if (n < N_SENSORY) v = thresh_clamp_inp(inp[b * ST + n * T_LAYERS + 0]);
        state[i] = v;
        acc[i]   = 0LL;
    }
}
__global__ void __launch_bounds__(256) k2_spmm(const float* __restrict__ vals,
                                               const int* __restrict__ rows,
                                               const int* __restrict__ cols,
                                               const float* __restrict__ state,
                                               long long* acc) {
    int tid = blockIdx.x * blockDim.x + threadIdx.x;
    int b = tid & 15;
    int e = tid >> 4;
    int estride = (gridDim.x * blockDim.x) >> 4;
    for (; e < NNZ_CNT; e += estride) {
        int   c  = cols[e];
        float xv = state[c * BATCH + b];
        float v  = vals[e];
        long long fx = llrintf(v * xv * FXSCALE);
        if (fx != 0LL) {
            int r = rows[e];
            atomicAdd((unsigned long long*)&acc[r * BATCH + b], (unsigned long long)fx);
        }
    }
}
__global__ void k2_act_inject(long long* acc, const float* __restrict__ inp,
                              float* __restrict__ state, float* __restrict__ out, int t) {
    int stride = gridDim.x * blockDim.x;
    for (int i = blockIdx.x * blockDim.x + threadIdx.x; i < NB; i += stride) {
        int n = i >> 4, b = i & 15;
        float y = (float)((double)acc[i] * FXINV);
        acc[i] = 0LL;
        float v = activate(y);
        if (n < N_SENSORY) v += thresh_clamp_inp(inp[b * ST + n * T_LAYERS + (t + 1)]);
        v = fminf(v, 1.0f);
        state[i] = v;
        out[b * NT + n * T_LAYERS + t] = v;
    }
}
__global__ void k2_act_final(const long long* __restrict__ acc, float* __restrict__ out) {
    int stride = gridDim.x * blockDim.x;
    for (int i = blockIdx.x * blockDim.x + threadIdx.x; i < NB; i += stride) {
        int n = i >> 4, b = i & 15;
        float y = (float)((double)acc[i] * FXINV);
        out[b * NT + n * T_LAYERS + (T_LAYERS - 1)] = activate(y);
    }
}

extern "C" void kernel_launch(void* const* d_in, const int* in_sizes, int n_in,
                              void* d_out, int out_size, void* d_ws, size_t ws_size,
                              hipStream_t stream) {
    const float* inputs = (const float*)d_in[0];   // (16, 5000, 8) f32
    const float* vals   = (const float*)d_in[1];   // (3.2M,) f32
    const int*   rows   = (const int*)  d_in[2];   // (3.2M,) i32
    const int*   cols   = (const int*)  d_in[3];   // (3.2M,) i32
    float* out = (float*)d_out;

    // ws layout (CSR path)
    const size_t sz_planes = (size_t)T_LAYERS * NB * 4;   // 51.2 MB
    const size_t sz_packed = (size_t)NNZ_CNT * 8;         // 25.6 MB
    const size_t sz_rowptr = ((size_t)N_NEURONS + 2) * 4;
    const size_t sz_btotal = (size_t)(NBUCKET + 8) * 4;
    const size_t sz_bbase  = (size_t)(NBUCKET + 8) * 4;
    const size_t sz_bcur   = (size_t)(NBUCKET + 8) * 4;
    const size_t REQ = sz_planes + sz_packed + sz_rowptr + sz_btotal + sz_bbase + sz_bcur;

    const int block = 256;

    if (ws_size >= REQ) {
        char* ws = (char*)d_ws;
        float* planes  = (float*)ws;
        int2*  packed  = (int2*)(ws + sz_planes);
        int*   row_ptr = (int*)(ws + sz_planes + sz_packed);
        int*   btotal  = (int*)(ws + sz_planes + sz_packed + sz_rowptr);
        int*   bbase   = (int*)(ws + sz_planes + sz_packed + sz_rowptr + sz_btotal);
        int*   bcur    = (int*)(ws + sz_planes + sz_packed + sz_rowptr + sz_btotal + sz_bbase);
        float* state0  = planes + (size_t)(T_LAYERS - 1) * NB;  // planes[7] slot
        int2*  packed_tmp = (int2*)planes;  // aliases planes[0..3]; dead before layer 0 runs

        const int grid_nb = (NB + block - 1) / block;           // 6250

        k_init<<<grid_nb, block, 0, stream>>>(inputs, state0, btotal);
        k_bcount<<<NBLK_A, 1024, 0, stream>>>(rows, btotal);
        k_bscan<<<1, 256, 0, stream>>>(btotal, bbase, bcur, row_ptr);
        k_passA<<<NBLK_A, 1024, 0, stream>>>(vals, rows, cols, bcur, packed_tmp);
        k_passB<<<NBUCKET, 1024, 0, stream>>>(bbase, packed_tmp, packed, row_ptr);

        for (int t = 0; t < T_LAYERS; ++t) {
            const float* sin_ = (t == 0) ? state0 : planes + (size_t)(t - 1) * NB;
            k_layer<<<grid_nb, block, 0, stream>>>(row_ptr, packed, sin_, inputs,
                                                   planes + (size_t)t * NB, t);
        }
        k_out<<<grid_nb, block, 0, stream>>>(planes, out);
    } else {
        // fallback: atomic path (19.2 MB ws)
        long long* acc   = (long long*)d_ws;
        float*     state = (float*)(acc + NB);
        const int grid_ew = 2048, grid_sp = 2048;
        k2_init<<<grid_ew, block, 0, stream>>>(inputs, state, acc);
        for (int t = 0; t < T_LAYERS; ++t) {
            k2_spmm<<<grid_sp, block, 0, stream>>>(vals, rows, cols, state, acc);
            if (t < T_LAYERS - 1)
                k2_act_inject<<<grid_ew, block, 0, stream>>>(acc, inputs, state, out, t);
            else
                k2_act_final<<<grid_ew, block, 0, stream>>>(acc, out);
        }
    }
}